// Round 2
// baseline (6215.116 us; speedup 1.0000x reference)
//
#include <hip/hip_runtime.h>
#include <math.h>

#define NN 256
#define BB 1024
#define NMAT 1025   // 1024 batch matrices + 1 for L0

// Static device storage (rewritten every launch)
__device__ float g_T[4][NN*NN];      // T[c][j*256+i] = Ws(i,j)*E(i,j,a,b)/(V[i][a]V[j][b]), c=2a+b
__device__ float g_Ws[NN*NN];        // Ws[j*256+i] (symmetric)
__device__ float g_V[NN][2];
__device__ float g_ld[NMAT];

__device__ __forceinline__ float sigmf(float v) { return 1.0f / (1.0f + expf(-v)); }

__global__ void k_prep_v(const float* __restrict__ Vc) {
  int i = threadIdx.x;
  float a = sigmf(Vc[2*i]);
  float b = sigmf(Vc[2*i+1]);
  float s = a + b;
  g_V[i][0] = a / s;
  g_V[i][1] = b / s;
}

__global__ void k_prep_T(const float* __restrict__ W, const float* __restrict__ lam) {
  int j = blockIdx.x;
  int i = threadIdx.x;
  float vi0 = g_V[i][0], vi1 = g_V[i][1];
  float vj0 = g_V[j][0], vj1 = g_V[j][1];
  float ws;
  if (i > j)      ws = sigmf(W[i*NN + j]);
  else if (i < j) ws = sigmf(W[j*NN + i]);
  else            ws = 0.0f;
  g_Ws[j*NN + i] = ws;
  float s = sigmf(lam[i*NN + j]);
  float pi = vi0, pj = vj0;
  float lower = fmaxf(1e-7f, pi + pj - 1.0f);
  float upper = fminf(pi, pj);
  float P00 = lower + s * (upper - lower);
  float P01 = pi - P00;
  float P10 = pj - P00;
  float P11 = 1.0f - pi - pj + P00;
  if (i == j) { P00 = P01 = P10 = P11 = 0.0f; }
  P00 = fminf(fmaxf(P00, 0.0f), 1.0f);
  P01 = fminf(fmaxf(P01, 0.0f), 1.0f);
  P10 = fminf(fmaxf(P10, 0.0f), 1.0f);
  P11 = fminf(fmaxf(P11, 0.0f), 1.0f);
  int o = j*NN + i;
  g_T[0][o] = ws * P00 / (vi0 * vj0);
  g_T[1][o] = ws * P01 / (vi0 * vj1);
  g_T[2][o] = ws * P10 / (vi1 * vj0);
  g_T[3][o] = ws * P11 / (vi1 * vj1);
}

// ---- register-resident LU helpers (all indices compile-time after unroll) ----
#define TAILQ(arr, base)                                                  \
  { _Pragma("unroll")                                                     \
    for (int q = 0; q < 16; ++q) {                                        \
      float4 u4 = *(const float4*)&urow[cur][(base) + 4*q];               \
      arr[4*q+0] -= mlt*u4.x; arr[4*q+1] -= mlt*u4.y;                     \
      arr[4*q+2] -= mlt*u4.z; arr[4*q+3] -= mlt*u4.w; } }

#define ACTHEAD(arr, base, kkv)                                           \
  { _Pragma("unroll")                                                     \
    for (int j = (kkv)+1; j < (((kkv)+4)&~3) && j < 64; ++j)              \
      arr[j] -= mlt*urow[cur][(base)+j];                                  \
    _Pragma("unroll")                                                     \
    for (int q = ((kkv)+4)>>2; q < 16; ++q) {                             \
      float4 u4 = *(const float4*)&urow[cur][(base)+4*q];                 \
      arr[4*q+0] -= mlt*u4.x; arr[4*q+1] -= mlt*u4.y;                     \
      arr[4*q+2] -= mlt*u4.z; arr[4*q+3] -= mlt*u4.w; } }

#define OSTQ(arr, base, q, nb)                                            \
  *(float4*)&urow[nb][(base)+4*(q)] =                                     \
      make_float4(arr[4*(q)], arr[4*(q)+1], arr[4*(q)+2], arr[4*(q)+3]);

#define OSTORE_FULL(arr, base, nb)                                        \
  { _Pragma("unroll") for (int q = 0; q < 16; ++q) { OSTQ(arr, base, q, nb) } }

#define OSTORE_FROM(arr, base, q0, nb)                                    \
  { _Pragma("unroll") for (int q = (q0); q < 16; ++q) { OSTQ(arr, base, q, nb) } }

// One workgroup per matrix; thread t owns full row t in 256 VGPRs.
// Unblocked right-looking no-pivot LU (row-diagonally-dominant => stable),
// one barrier per step, double-buffered LDS broadcast row.
__global__ __launch_bounds__(256, 1) void k_lu(const int* __restrict__ x) {
  __shared__ __align__(16) float urow[2][NN];
  __shared__ float pivbuf[NN];
  __shared__ int   xs[NN];
  __shared__ float red[4];

  const int t = threadIdx.x;
  const int m = blockIdx.x;

  if (m < BB) xs[t] = x[m*NN + t];
  __syncthreads();

  float r0[64], r1[64], r2[64], r3[64];
  float rowsum = 0.0f;

  // ---- build row t of the shifted (drop row/col 0) padded matrix ----
  if (m < BB) {
    const int a = (t < 255) ? xs[t+1] : 0;
    const float* TA = &g_T[0][0] + (size_t)a*(2*NN*NN) + (t+1);
    #pragma unroll
    for (int c = 0; c < 64; ++c) { int b = xs[c+1];   float w = TA[(size_t)b*(NN*NN)+(size_t)(c+1)*NN];   rowsum += w; r0[c] = -w; }
    #pragma unroll
    for (int c = 0; c < 64; ++c) { int b = xs[c+65];  float w = TA[(size_t)b*(NN*NN)+(size_t)(c+65)*NN];  rowsum += w; r1[c] = -w; }
    #pragma unroll
    for (int c = 0; c < 64; ++c) { int b = xs[c+129]; float w = TA[(size_t)b*(NN*NN)+(size_t)(c+129)*NN]; rowsum += w; r2[c] = -w; }
    #pragma unroll
    for (int c = 0; c < 63; ++c) { int b = xs[c+193]; float w = TA[(size_t)b*(NN*NN)+(size_t)(c+193)*NN]; rowsum += w; r3[c] = -w; }
    rowsum += TA[(size_t)xs[0]*(NN*NN)];
  } else {
    const float* WS = g_Ws + ((t < 255) ? (t+1) : 0);
    #pragma unroll
    for (int c = 0; c < 64; ++c) { float w = WS[(size_t)(c+1)*NN];   rowsum += w; r0[c] = -w; }
    #pragma unroll
    for (int c = 0; c < 64; ++c) { float w = WS[(size_t)(c+65)*NN];  rowsum += w; r1[c] = -w; }
    #pragma unroll
    for (int c = 0; c < 64; ++c) { float w = WS[(size_t)(c+129)*NN]; rowsum += w; r2[c] = -w; }
    #pragma unroll
    for (int c = 0; c < 63; ++c) { float w = WS[(size_t)(c+193)*NN]; rowsum += w; r3[c] = -w; }
    rowsum += WS[0];
  }
  r3[63] = 0.0f;

  // diagonal (column t) = rowsum
  #pragma unroll
  for (int c = 0; c < 64; ++c) if (t == c)       r0[c] = rowsum;
  #pragma unroll
  for (int c = 0; c < 64; ++c) if (t == 64 + c)  r1[c] = rowsum;
  #pragma unroll
  for (int c = 0; c < 64; ++c) if (t == 128 + c) r2[c] = rowsum;
  #pragma unroll
  for (int c = 0; c < 63; ++c) if (t == 192 + c) r3[c] = rowsum;

  // pad row 255 = e_255
  if (t == 255) {
    #pragma unroll
    for (int c = 0; c < 64; ++c) { r0[c] = 0.f; r1[c] = 0.f; r2[c] = 0.f; r3[c] = 0.f; }
    r3[63] = 1.0f;
    pivbuf[255] = 1.0f;
  }

  // owner of step 0 broadcasts its row into buffer 0
  if (t == 0) {
    OSTORE_FULL(r0, 0,   0)
    OSTORE_FULL(r1, 64,  0)
    OSTORE_FULL(r2, 128, 0)
    OSTORE_FULL(r3, 192, 0)
    pivbuf[0] = r0[0];
  }

  // ---- phase 0: k = 0..62 ----
  #pragma unroll
  for (int kk = 0; kk < 63; ++kk) {
    __syncthreads();
    const int cur = kk & 1, nxt = cur ^ 1;
    if (t > kk) {
      float mlt = r0[kk] * __builtin_amdgcn_rcpf(urow[cur][kk]);
      r0[kk] = mlt;
      ACTHEAD(r0, 0, kk)
      TAILQ(r1, 64) TAILQ(r2, 128) TAILQ(r3, 192)
      if (t == kk + 1) {
        OSTORE_FROM(r0, 0, (kk+1)>>2, nxt)
        OSTORE_FULL(r1, 64, nxt) OSTORE_FULL(r2, 128, nxt) OSTORE_FULL(r3, 192, nxt)
        pivbuf[kk+1] = r0[kk+1];
      }
    }
  }
  // k = 63 (phase boundary)
  __syncthreads();
  {
    const int cur = 1, nxt = 0;
    if (t > 63) {
      float mlt = r0[63] * __builtin_amdgcn_rcpf(urow[cur][63]);
      r0[63] = mlt;
      TAILQ(r1, 64) TAILQ(r2, 128) TAILQ(r3, 192)
      if (t == 64) {
        OSTORE_FULL(r1, 64, nxt) OSTORE_FULL(r2, 128, nxt) OSTORE_FULL(r3, 192, nxt)
        pivbuf[64] = r1[0];
      }
    }
  }
  // ---- phase 1: k = 64..126 ----
  #pragma unroll
  for (int kk = 0; kk < 63; ++kk) {
    __syncthreads();
    const int k = 64 + kk;
    const int cur = k & 1, nxt = cur ^ 1;
    if (t > k) {
      float mlt = r1[kk] * __builtin_amdgcn_rcpf(urow[cur][k]);
      r1[kk] = mlt;
      ACTHEAD(r1, 64, kk)
      TAILQ(r2, 128) TAILQ(r3, 192)
      if (t == k + 1) {
        OSTORE_FROM(r1, 64, (kk+1)>>2, nxt)
        OSTORE_FULL(r2, 128, nxt) OSTORE_FULL(r3, 192, nxt)
        pivbuf[k+1] = r1[kk+1];
      }
    }
  }
  // k = 127
  __syncthreads();
  {
    const int cur = 1, nxt = 0;
    if (t > 127) {
      float mlt = r1[63] * __builtin_amdgcn_rcpf(urow[cur][127]);
      r1[63] = mlt;
      TAILQ(r2, 128) TAILQ(r3, 192)
      if (t == 128) {
        OSTORE_FULL(r2, 128, nxt) OSTORE_FULL(r3, 192, nxt)
        pivbuf[128] = r2[0];
      }
    }
  }
  // ---- phase 2: k = 128..190 ----
  #pragma unroll
  for (int kk = 0; kk < 63; ++kk) {
    __syncthreads();
    const int k = 128 + kk;
    const int cur = k & 1, nxt = cur ^ 1;
    if (t > k) {
      float mlt = r2[kk] * __builtin_amdgcn_rcpf(urow[cur][k]);
      r2[kk] = mlt;
      ACTHEAD(r2, 128, kk)
      TAILQ(r3, 192)
      if (t == k + 1) {
        OSTORE_FROM(r2, 128, (kk+1)>>2, nxt)
        OSTORE_FULL(r3, 192, nxt)
        pivbuf[k+1] = r2[kk+1];
      }
    }
  }
  // k = 191
  __syncthreads();
  {
    const int cur = 1, nxt = 0;
    if (t > 191) {
      float mlt = r2[63] * __builtin_amdgcn_rcpf(urow[cur][191]);
      r2[63] = mlt;
      TAILQ(r3, 192)
      if (t == 192) {
        OSTORE_FULL(r3, 192, nxt)
        pivbuf[192] = r3[0];
      }
    }
  }
  // ---- phase 3: k = 192..253 ----
  #pragma unroll
  for (int kk = 0; kk < 62; ++kk) {
    __syncthreads();
    const int k = 192 + kk;
    const int cur = k & 1, nxt = cur ^ 1;
    if (t > k) {
      float mlt = r3[kk] * __builtin_amdgcn_rcpf(urow[cur][k]);
      r3[kk] = mlt;
      ACTHEAD(r3, 192, kk)
      if (t == k + 1) {
        OSTORE_FROM(r3, 192, (kk+1)>>2, nxt)
        pivbuf[k+1] = r3[kk+1];
      }
    }
  }
  // k = 254 (final elimination step; only row 255 updates)
  __syncthreads();
  {
    const int cur = 0;
    if (t > 254) {
      float mlt = r3[62] * __builtin_amdgcn_rcpf(urow[cur][254]);
      r3[62] = mlt;
      r3[63] -= mlt * urow[cur][255];
    }
  }

  // ---- log|det| = sum log|u_kk| ----
  __syncthreads();
  float lg = logf(fabsf(pivbuf[t]));
  #pragma unroll
  for (int off = 32; off > 0; off >>= 1) lg += __shfl_down(lg, off, 64);
  if ((t & 63) == 0) red[t >> 6] = lg;
  __syncthreads();
  if (t == 0) g_ld[m] = red[0] + red[1] + red[2] + red[3];
}

__global__ void k_final(const int* __restrict__ x, float* __restrict__ out) {
  __shared__ float red[4];
  int b = blockIdx.x, t = threadIdx.x;
  int xv = x[b*NN + t];
  float lg = logf(g_V[t][xv]);
  #pragma unroll
  for (int off = 32; off > 0; off >>= 1) lg += __shfl_down(lg, off, 64);
  if ((t & 63) == 0) red[t >> 6] = lg;
  __syncthreads();
  if (t == 0) out[b] = (red[0] + red[1] + red[2] + red[3]) + g_ld[b] - g_ld[BB];
}

extern "C" void kernel_launch(void* const* d_in, const int* in_sizes, int n_in,
                              void* d_out, int out_size, void* d_ws, size_t ws_size,
                              hipStream_t stream) {
  const float* W   = (const float*)d_in[0];
  const float* lam = (const float*)d_in[1];
  const float* Vc  = (const float*)d_in[2];
  const int*   x   = (const int*)d_in[3];
  float* out = (float*)d_out;

  k_prep_v<<<dim3(1),    dim3(NN), 0, stream>>>(Vc);
  k_prep_T<<<dim3(NN),   dim3(NN), 0, stream>>>(W, lam);
  k_lu    <<<dim3(NMAT), dim3(NN), 0, stream>>>(x);
  k_final <<<dim3(BB),   dim3(NN), 0, stream>>>(x, out);
}